// Round 12
// baseline (329.200 us; speedup 1.0000x reference)
//
#include <hip/hip_runtime.h>
#include <math.h>

// Round 17: mlp_fused v5 — 8 rows/block x 512 blocks = 2 INDEPENDENT blocks
// per CU (R9's idea minus the dup-work bug). The 52.5us invariant across
// R10-R16 points at the single-block 12-barrier serial chain: with one block
// per CU, every vmcnt(0)+s_barrier stalls all resident waves. Two blocks at
// different phases interleave. Wave w owns 32 cols (2 n-tiles, wp0/wp1
// prefetch); MFMA rows 8-15 duplicate rows 0-7 (epilogues guard rr<8).
// attn/projections/unpack identical to round 16.

typedef short bf8 __attribute__((ext_vector_type(8)));
typedef short bf4 __attribute__((ext_vector_type(4)));
typedef float f32x4 __attribute__((ext_vector_type(4)));
typedef unsigned short u16;

constexpr int LDT = 40;  // LDS row stride in shorts (32 data + 8 pad)
enum { EPI_NONE = 0, EPI_BIAS_RELU = 1, EPI_BIAS = 2, EPI_RESID = 3 };
#define RSQRT2 0.70710678118654752f

__device__ __forceinline__ u16 f2bf(float f) {
  unsigned int u = __builtin_bit_cast(unsigned int, f);
  unsigned int r = u + 0x7fffu + ((u >> 16) & 1u);  // RNE
  return (u16)(r >> 16);
}
__device__ __forceinline__ float bf2f(u16 v) {
  return __builtin_bit_cast(float, (unsigned int)v << 16);
}
__device__ __forceinline__ f32x4 mfma16(bf8 a, bf8 b, f32x4 c) {
  return __builtin_amdgcn_mfma_f32_16x16x32_bf16(a, b, c, 0, 0, 0);
}

// ---------------- batched f32 -> bf16 conversion -----------------------------
struct CvtDesc { const float* src; u16* dst; int n; };
struct CvtArgs { CvtDesc d[8]; };

__global__ __launch_bounds__(256) void cvt_k(CvtArgs a) {
  CvtDesc d = a.d[blockIdx.z];
  int i = (blockIdx.x * 256 + threadIdx.x) * 8;
  if (i >= d.n) return;
  f32x4 v0 = *(const f32x4*)(d.src + i);
  f32x4 v1 = *(const f32x4*)(d.src + i + 4);
  bf8 o;
  o[0] = (short)f2bf(v0[0]); o[1] = (short)f2bf(v0[1]);
  o[2] = (short)f2bf(v0[2]); o[3] = (short)f2bf(v0[3]);
  o[4] = (short)f2bf(v1[0]); o[5] = (short)f2bf(v1[1]);
  o[6] = (short)f2bf(v1[2]); o[7] = (short)f2bf(v1[3]);
  *(bf8*)(d.dst + i) = o;
}

// ------- MTxN-tile bf16 GEMM: C[M,N] = A[M,K](bf16) @ B[N,K](bf16)^T --------
template <int EPI, bool BFOUT, int MT>
__global__ __launch_bounds__(256) void mgemm2(
    const u16* __restrict__ A, const u16* __restrict__ B,
    void* __restrict__ Cv, int M, int N, int K, int lda, int ldb, int ldc,
    const float* __restrict__ bias, const float* __restrict__ Hin,
    const int* __restrict__ gatherA, const int* __restrict__ scatterC) {
  constexpr int NF = MT / 32;  // m-frags per wave
  __shared__ __align__(16) u16 As[MT * LDT];
  __shared__ __align__(16) u16 Bs[64 * LDT];
  const int tid = threadIdx.x;
  const int m0 = blockIdx.y * MT, n0 = blockIdx.x * 64;
  const int wave = tid >> 6, lane = tid & 63;
  const int wm = (wave & 1) * (MT / 2), wn = (wave >> 1) * 32;
  const int lrow = lane & 15, quad = lane >> 4;
  const int srow = tid >> 2, skq = tid & 3;

  int gr0 = m0 + srow;
  int ar0 = (gr0 < M) ? (gatherA ? gatherA[gr0] : gr0) : -1;
  const u16* Ap0 = (ar0 >= 0) ? A + (size_t)ar0 * lda + skq * 8 : nullptr;
  const u16* Ap1 = nullptr;
  if constexpr (MT == 128) {
    int gr1 = m0 + srow + 64;
    int ar1 = (gr1 < M) ? (gatherA ? gatherA[gr1] : gr1) : -1;
    Ap1 = (ar1 >= 0) ? A + (size_t)ar1 * lda + skq * 8 : nullptr;
  }
  const u16* Bp = (n0 + srow < N) ? B + (size_t)(n0 + srow) * ldb + skq * 8 : nullptr;
  u16* AsW0 = &As[srow * LDT + skq * 8];
  u16* AsW1 = (MT == 128) ? &As[(srow + 64) * LDT + skq * 8] : nullptr;
  u16* BsW = &Bs[srow * LDT + skq * 8];

  f32x4 acc[NF][2];
#pragma unroll
  for (int i = 0; i < NF; ++i)
#pragma unroll
    for (int j = 0; j < 2; ++j) acc[i][j] = (f32x4){0.f, 0.f, 0.f, 0.f};
  const bf8 z8 = {0, 0, 0, 0, 0, 0, 0, 0};

  for (int k0 = 0; k0 < K; k0 += 32) {
    bf8 a0 = Ap0 ? *(const bf8*)(Ap0 + k0) : z8;
    bf8 bv = Bp ? *(const bf8*)(Bp + k0) : z8;
    *(bf8*)AsW0 = a0;
    if constexpr (MT == 128) {
      bf8 a1 = Ap1 ? *(const bf8*)(Ap1 + k0) : z8;
      *(bf8*)AsW1 = a1;
    }
    *(bf8*)BsW = bv;
    __syncthreads();
    bf8 af[NF], bfr[2];
#pragma unroll
    for (int i = 0; i < NF; ++i)
      af[i] = *(const bf8*)&As[(wm + i * 16 + lrow) * LDT + quad * 8];
#pragma unroll
    for (int j = 0; j < 2; ++j)
      bfr[j] = *(const bf8*)&Bs[(wn + j * 16 + lrow) * LDT + quad * 8];
#pragma unroll
    for (int i = 0; i < NF; ++i)
#pragma unroll
      for (int j = 0; j < 2; ++j) acc[i][j] = mfma16(af[i], bfr[j], acc[i][j]);
    __syncthreads();
  }

  float* Cf = (float*)Cv;
  u16* Cb = (u16*)Cv;
#pragma unroll
  for (int i = 0; i < NF; ++i) {
#pragma unroll
    for (int r = 0; r < 4; ++r) {
      int row = m0 + wm + i * 16 + quad * 4 + r;
      if (row >= M) continue;
      if (gatherA && gatherA[row] < 0) continue;
      int orow = scatterC ? scatterC[row] : row;
#pragma unroll
      for (int j = 0; j < 2; ++j) {
        int col = n0 + wn + j * 16 + lrow;
        if (col >= N) continue;
        float v = acc[i][j][r];
        if (EPI == EPI_BIAS_RELU) v = fmaxf(v + bias[col], 0.f);
        else if (EPI == EPI_BIAS) v += bias[col];
        else if (EPI == EPI_RESID) v = (Hin[(size_t)row * ldc + col] + v + bias[col]) * RSQRT2;
        if (BFOUT) Cb[(size_t)orow * ldc + col] = f2bf(v);
        else Cf[(size_t)orow * ldc + col] = v;
      }
    }
  }
}

// ---------------- V transpose: KV[b][s][512+hd] -> VT[b][hd][s] (bf16) -------
__global__ __launch_bounds__(256) void vtrans(const u16* __restrict__ KV,
                                              u16* __restrict__ VT) {
  __shared__ u16 t[32][33];
  int b = blockIdx.z;
  int s0 = blockIdx.x * 32, d0 = blockIdx.y * 32;
  int tx = threadIdx.x & 31, ty = threadIdx.x >> 5;
#pragma unroll
  for (int i = 0; i < 32; i += 8)
    t[ty + i][tx] = KV[(size_t)(b * 512 + s0 + ty + i) * 1024 + 512 + d0 + tx];
  __syncthreads();
#pragma unroll
  for (int i = 0; i < 32; i += 8)
    VT[(size_t)(b * 512 + d0 + ty + i) * 512 + s0 + tx] = t[tx][ty + i];
}

// ---------------- fused attention: per (b,h,mtile32) -------------------------
constexpr int WST = 520;  // W row stride (512 + 8 pad) -> 65 granules (odd)
constexpr int QST = 72;   // K/V row stride (64 + 8 pad) -> 9 granules (odd)

__global__ __launch_bounds__(256) void attn_fused(
    const u16* __restrict__ Q, const u16* __restrict__ KV,
    const u16* __restrict__ VT, const int* __restrict__ list,
    const float* __restrict__ mask, u16* __restrict__ packed,
    u16* __restrict__ feat, int N) {
  // XCD-aware decode: lin = xcd + 8*(mt + NMT*(y>>3)); y = (group<<3)|xcd
  const int NMT = gridDim.x;              // mt tiles per (b,h)
  const int lin = blockIdx.y * NMT + blockIdx.x;
  const int xcd = lin & 7, rest = lin >> 3;
  const int mt = rest % NMT;
  const int y = ((rest / NMT) << 3) | xcd;
  const int b = y >> 3, h = y & 7;
  const int* lst = list + (size_t)b * N + mt * 32;
  if (lst[0] < 0) return;

  __shared__ __align__(16) u16 Ws[32 * WST];
  __shared__ __align__(16) u16 KVs[2][64 * QST];  // ping-pong K tiles / V chunks
  __shared__ int mS[32];

  const int tid = threadIdx.x;
  const int wave = tid >> 6, lane = tid & 63;
  const int wm = (wave & 1) * 16, wns = (wave >> 1) * 32;
  const int lrow = lane & 15, quad = lane >> 4;
  const bf8 z8 = {0, 0, 0, 0, 0, 0, 0, 0};

  // staging lane geometry (shared by Phase A / Phase B)
  const int c0 = tid * 2, c1 = tid * 2 + 1;
  const int sr0 = c0 >> 3, kq0 = c0 & 7;
  const int sr1 = c1 >> 3, kq1 = c1 & 7;
  const int o0 = sr0 * QST + kq0 * 8, o1 = sr1 * QST + kq1 * 8;

  const u16* KVb = KV + (size_t)(b * 512) * 1024 + h * 64;
  const u16* VTb = VT + (size_t)(b * 512 + h * 64) * 512;

  if (tid < 32) mS[tid] = lst[tid];
  {  // prologue: stage K tile rot(0) into KVs[0]
    int sta = mt & 7;
    *(bf8*)&KVs[0][o0] = *(const bf8*)(KVb + (size_t)(sta * 64 + sr0) * 1024 + kq0 * 8);
    *(bf8*)&KVs[0][o1] = *(const bf8*)(KVb + (size_t)(sta * 64 + sr1) * 1024 + kq1 * 8);
  }
  __syncthreads();

  // Q fragments direct from global (one 2x16B read per lane, never re-read)
  const int qrow = mS[wm + lrow];
  const u16* Qr = Q + (size_t)qrow * 512 + h * 64 + quad * 8;
  const bf8 qa0 = (qrow >= 0) ? *(const bf8*)Qr : z8;
  const bf8 qa1 = (qrow >= 0) ? *(const bf8*)(Qr + 32) : z8;

  // ---- Phase A: scores; dbuf -> ONE barrier per phase (T14 reg prefetch) ----
  int cur = 0;
  bf8 r0, r1;
  for (int st = 0; st < 8; ++st) {
    const int sta = (st + mt) & 7;
    if (st < 7) {  // issue next-tile loads early; drained before LDS write
      int nx = (st + 1 + mt) & 7;
      r0 = *(const bf8*)(KVb + (size_t)(nx * 64 + sr0) * 1024 + kq0 * 8);
      r1 = *(const bf8*)(KVb + (size_t)(nx * 64 + sr1) * 1024 + kq1 * 8);
    }
    f32x4 acc0 = {0.f, 0.f, 0.f, 0.f}, acc1 = acc0;
    {
      bf8 b00 = *(const bf8*)&KVs[cur][(wns + lrow) * QST + quad * 8];
      bf8 b10 = *(const bf8*)&KVs[cur][(wns + 16 + lrow) * QST + quad * 8];
      bf8 b01 = *(const bf8*)&KVs[cur][(wns + lrow) * QST + 32 + quad * 8];
      bf8 b11 = *(const bf8*)&KVs[cur][(wns + 16 + lrow) * QST + 32 + quad * 8];
      __builtin_amdgcn_s_setprio(1);
      acc0 = mfma16(qa0, b00, acc0);
      acc1 = mfma16(qa0, b10, acc1);
      acc0 = mfma16(qa1, b01, acc0);
      acc1 = mfma16(qa1, b11, acc1);
      __builtin_amdgcn_s_setprio(0);
    }
#pragma unroll
    for (int r = 0; r < 4; ++r) {
      int lr = wm + quad * 4 + r;
      Ws[lr * WST + sta * 64 + wns + lrow] = f2bf(acc0[r] * 0.125f);
      Ws[lr * WST + sta * 64 + wns + 16 + lrow] = f2bf(acc1[r] * 0.125f);
    }
    if (st < 7) {  // write next tile into the OTHER buffer (no fence needed)
      *(bf8*)&KVs[cur ^ 1][o0] = r0;
      *(bf8*)&KVs[cur ^ 1][o1] = r1;
    }
    __syncthreads();  // next buffer ready + (last iter) Ws visible for stats
    cur ^= 1;
  }

  // Phase-B prologue: first V chunk loads issued BEFORE stats (hidden there)
  bf8 v0p = *(const bf8*)(VTb + (size_t)sr0 * 512 + ((mt & 7) << 6) + kq0 * 8);
  bf8 v1p = *(const bf8*)(VTb + (size_t)sr1 * 512 + ((mt & 7) << 6) + kq1 * 8);

  // ---- Stats + W rebuild: mask direct from global; ev cached in VGPRs ----
  {
    const int row = tid >> 3, part = tid & 7;
    u16* wrow = &Ws[row * WST + part * 64];
    const int mm = mS[row];
    const float* mkp = mask + (size_t)b * 512 + part * 64;
    bf8 w[8];
    float mx = -1e30f;
#pragma unroll
    for (int v = 0; v < 8; ++v) {
      w[v] = *(const bf8*)(wrow + v * 8);
#pragma unroll
      for (int j = 0; j < 8; ++j) mx = fmaxf(mx, bf2f((u16)w[v][j]));
    }
    if (mm >= 0) {  // packed raw scores, 16B coalesced stores
      u16* prow = packed + ((size_t)h * N + mm) * 512 + part * 64;
#pragma unroll
      for (int v = 0; v < 8; ++v) *(bf8*)(prow + v * 8) = w[v];
    }
#pragma unroll
    for (int d = 1; d < 8; d <<= 1) mx = fmaxf(mx, __shfl_xor(mx, d));
    float ev[64];
    float se = 0.f, ms = 0.f;
#pragma unroll
    for (int v = 0; v < 8; ++v) {
      f32x4 m0 = *(const f32x4*)(mkp + v * 8);
      f32x4 m1 = *(const f32x4*)(mkp + v * 8 + 4);
#pragma unroll
      for (int j = 0; j < 8; ++j) {
        float e = __expf(bf2f((u16)w[v][j]) - mx);
        ev[v * 8 + j] = e;
        se += e;
        ms += e * (j < 4 ? m0[j] : m1[j - 4]);
      }
    }
#pragma unroll
    for (int d = 1; d < 8; d <<= 1) {
      se += __shfl_xor(se, d);
      ms += __shfl_xor(ms, d);
    }
    float iv = 1.0f / (ms + 1e-6f * se);
#pragma unroll
    for (int v = 0; v < 8; ++v) {
      f32x4 m0 = *(const f32x4*)(mkp + v * 8);
      f32x4 m1 = *(const f32x4*)(mkp + v * 8 + 4);
      bf8 o;
#pragma unroll
      for (int j = 0; j < 8; ++j)
        o[j] = (short)f2bf(ev[v * 8 + j] * (j < 4 ? m0[j] : m1[j - 4]) * iv);
      *(bf8*)(wrow + v * 8) = o;
    }
  }
  __syncthreads();  // Ws rebuilt visible; Phase-A KVs reads long done
  *(bf8*)&KVs[0][o0] = v0p;
  *(bf8*)&KVs[0][o1] = v1p;
  __syncthreads();  // V chunk rot(0) ready

  // ---- Phase B: feat = W @ VT^T (32m x 64d, K=512), dbuf, 1 barrier/phase --
  f32x4 acc0 = {0.f, 0.f, 0.f, 0.f}, acc1 = acc0;
  cur = 0;
  for (int ss = 0; ss < 8; ++ss) {
    const int s0 = ((ss + mt) & 7) << 6;
    if (ss < 7) {  // issue next-chunk loads early
      int nx = ((ss + 1 + mt) & 7) << 6;
      v0p = *(const bf8*)(VTb + (size_t)sr0 * 512 + nx + kq0 * 8);
      v1p = *(const bf8*)(VTb + (size_t)sr1 * 512 + nx + kq1 * 8);
    }
#pragma unroll
    for (int k0 = 0; k0 < 64; k0 += 32) {
      bf8 a = *(const bf8*)&Ws[(wm + lrow) * WST + s0 + k0 + quad * 8];
      bf8 b0 = *(const bf8*)&KVs[cur][(wns + lrow) * QST + k0 + quad * 8];
      bf8 b1 = *(const bf8*)&KVs[cur][(wns + 16 + lrow) * QST + k0 + quad * 8];
      __builtin_amdgcn_s_setprio(1);
      acc0 = mfma16(a, b0, acc0);
      acc1 = mfma16(a, b1, acc1);
      __builtin_amdgcn_s_setprio(0);
    }
    if (ss < 7) {
      *(bf8*)&KVs[cur ^ 1][o0] = v0p;
      *(bf8*)&KVs[cur ^ 1][o1] = v1p;
      __syncthreads();  // next chunk ready
    }
    cur ^= 1;
  }
#pragma unroll
  for (int r = 0; r < 4; ++r) {
    int lr = wm + quad * 4 + r;
    int mm = mS[lr];
    if (mm < 0) continue;
    u16* frow = feat + (size_t)mm * 512 + h * 64;
    frow[wns + lrow] = f2bf(acc0[r]);
    frow[wns + 16 + lrow] = f2bf(acc1[r]);
  }
}

// ---------------- unpack: packed[h][m][s] -> out_sc[pm[m]][s][h] fp32 --------
__global__ __launch_bounds__(256) void unpack_k(const u16* __restrict__ packed,
                                                const int* __restrict__ pm,
                                                float* __restrict__ out_sc,
                                                int N) {
  __shared__ u16 Ls[8 * 520];
  int m = blockIdx.x, tid = threadIdx.x;
  int h = tid >> 5, c = (tid & 31) * 16;
  const u16* row = packed + ((size_t)h * N + m) * 512 + c;
  *(bf8*)&Ls[h * 520 + c] = *(const bf8*)row;
  *(bf8*)&Ls[h * 520 + c + 8] = *(const bf8*)(row + 8);
  __syncthreads();
  float* orow = out_sc + (size_t)pm[m] * 4096;
#pragma unroll
  for (int i = 0; i < 16; ++i) {
    int e = tid + i * 256;
    orow[e] = bf2f(Ls[(e & 7) * 520 + (e >> 3)]);
  }
}

// ------- fused: LN512(feat) -> ag -> out_x -> 3x residual MLP -> head --------
// 8 rows/block (512 blocks = 2 independent blocks/CU), 512 threads (8 waves).
// Wave w owns cols [w*32, w*32+32) (2 n-tiles, wp0/wp1 rolling prefetch);
// wave r owns row r for LN/outx/head. MFMA A rows 8-15 duplicate rows 0-7
// (As read with lrow&7); epilogues guard rr<8.
constexpr int HST = 268;   // Hs row stride in floats (67 granules, odd)
constexpr int AST = 520;   // As row stride in shorts (65 granules, odd)
constexpr int YST = 280;   // Ys row stride in shorts (35 granules, odd)

__global__ __launch_bounds__(512, 4) void mlp_fused(
    const u16* __restrict__ feat, const float* __restrict__ ag_s,
    const float* __restrict__ ag_b, const u16* __restrict__ Wag,
    const float* __restrict__ x, const float* __restrict__ ens,
    const float* __restrict__ enb, const float* __restrict__ rls,
    const float* __restrict__ rlb, const u16* __restrict__ rw1,
    const float* __restrict__ rb1, const u16* __restrict__ rw2,
    const float* __restrict__ rb2, const float* __restrict__ hw,
    const float* __restrict__ hb, const int* __restrict__ pm,
    float* __restrict__ out_lg, float* __restrict__ out_x) {
  __shared__ __align__(16) float Hs[8 * HST];
  __shared__ __align__(16) u16 As[8 * AST];   // LN outputs (512 or 256 wide)
  __shared__ __align__(16) u16 Ys[8 * YST];   // relu(GEMM1) outputs
  const int tid = threadIdx.x;
  const int m0 = blockIdx.x * 8;
  const int wave = tid >> 6, lane = tid & 63;
  const int lrow = lane & 15, quad = lane >> 4;
  const int ar = lrow & 7;    // A-fragment source row (rows 8-15 dup 0-7)
  const int wn = wave * 32;   // this wave's 32 output cols (2 n-tiles)
  const int row = wave;       // LN/outx/head: wave r owns row r
  const int wq8 = quad * 8;
  const int nrow = pm[m0 + row];  // original row index for this wave's row

  // per-thread weight-fragment row pointers for the two n-tiles
  const u16* Wag0 = Wag + (size_t)(wn + lrow) * 512 + wq8;
  const u16* Wag1 = Wag + (size_t)(wn + 16 + lrow) * 512 + wq8;
  const u16* W1a = rw1 + (size_t)(wn + lrow) * 256 + wq8;    // + layer*65536
  const u16* W1b = rw1 + (size_t)(wn + 16 + lrow) * 256 + wq8;
  const u16* W2a = rw2 + (size_t)(wn + lrow) * 256 + wq8;
  const u16* W2b = rw2 + (size_t)(wn + 16 + lrow) * 256 + wq8;

  // prefetch AG first half (k = 0..255) — hidden under LN512 + barrier
  bf8 wp0[8], wp1[8];
#pragma unroll
  for (int i = 0; i < 8; ++i) {
    wp0[i] = *(const bf8*)(Wag0 + i * 32);
    wp1[i] = *(const bf8*)(Wag1 + i * 32);
  }

  // ---- LN512(feat) -> As (bf16), 8 cols per lane ----
  {
    const u16* frow = feat + (size_t)(m0 + row) * 512 + lane * 8;
    bf8 f0 = *(const bf8*)frow;
    float s = 0.f, sq = 0.f;
#pragma unroll
    for (int j = 0; j < 8; ++j) {
      float a = bf2f((u16)f0[j]);
      s += a;
      sq += a * a;
    }
#pragma unroll
    for (int d = 1; d < 64; d <<= 1) { s += __shfl_xor(s, d); sq += __shfl_xor(sq, d); }
    float mean = s * (1.0f / 512.0f);
    float var = sq * (1.0f / 512.0f) - mean * mean;
    float is = 1.0f / sqrtf(var + 1e-5f);
    int c = lane * 8;
    bf8 o0;
#pragma unroll
    for (int j = 0; j < 8; ++j)
      o0[j] = (short)f2bf((bf2f((u16)f0[j]) - mean) * is * ag_s[c + j] + ag_b[c + j]);
    *(bf8*)&As[row * AST + c] = o0;
  }
  __syncthreads();

  // ---- AG GEMM: h = ag = LN(feat) @ Wag^T (K=512, two halves of 8) ----
  {
    f32x4 acc0 = {0.f, 0.f, 0.f, 0.f}, acc1 = acc0;
#pragma unroll
    for (int i = 0; i < 8; ++i) {       // consume k 0..255, refill k 256..511
      bf8 a = *(const bf8*)&As[ar * AST + i * 32 + wq8];
      acc0 = mfma16(a, wp0[i], acc0);
      acc1 = mfma16(a, wp1[i], acc1);
      wp0[i] = *(const bf8*)(Wag0 + 256 + i * 32);
      wp1[i] = *(const bf8*)(Wag1 + 256 + i * 32);
    }
#pragma unroll
    for (int i = 0; i < 8; ++i) {       // consume k 256..511, refill W1[0]
      bf8 a = *(const bf8*)&As[ar * AST + 256 + i * 32 + wq8];
      acc0 = mfma16(a, wp0[i], acc0);
      acc1 = mfma16(a, wp1[i], acc1);
      wp0[i] = *(const bf8*)(W1a + i * 32);
      wp1[i] = *(const bf8*)(W1b + i * 32);
    }
#pragma unroll
    for (int r = 0; r < 4; ++r) {
      int rr = quad * 4 + r;
      if (rr < 8) {
        Hs[rr * HST + wn + lrow] = acc0[r];
        Hs[rr * HST + wn + 16 + lrow] = acc1[r];
      }
    }
  }
  __syncthreads();  // Hs = ag complete

  // ---- out_x = LN(x + ag/sqrt2) for this block's 8 rows (fused outx) ----
  {
    int c = lane * 4;
    f32x4 xv = *(const f32x4*)&x[(size_t)nrow * 256 + c];
    f32x4 hv = *(const f32x4*)&Hs[row * HST + c];
    f32x4 v;
#pragma unroll
    for (int e = 0; e < 4; ++e) v[e] = xv[e] + hv[e] * RSQRT2;
    float s = v[0] + v[1] + v[2] + v[3];
    float sq = v[0] * v[0] + v[1] * v[1] + v[2] * v[2] + v[3] * v[3];
#pragma unroll
    for (int d = 1; d < 64; d <<= 1) { s += __shfl_xor(s, d); sq += __shfl_xor(sq, d); }
    float mean = s * (1.0f / 256.0f);
    float var = sq * (1.0f / 256.0f) - mean * mean;
    float is = 1.0f / sqrtf(var + 1e-5f);
    f32x4 o;
#pragma unroll
    for (int e = 0; e < 4; ++e)
      o[e] = (v[e] - mean) * is * ens[c + e] + enb[c + e];
    *(f32x4*)&out_x[(size_t)nrow * 256 + c] = o;
  }

  // ---- 3 residual layers ----
  for (int layer = 0; layer < 3; ++layer) {
    // LN(h) -> As (4 cols per lane)   [Hs stable since the barrier above]
    {
      int c = lane * 4;
      f32x4 h0 = *(const f32x4*)&Hs[row * HST + c];
      float s = h0[0] + h0[1] + h0[2] + h0[3];
      float sq = h0[0] * h0[0] + h0[1] * h0[1] + h0[2] * h0[2] + h0[3] * h0[3];
#pragma unroll
      for (int d = 1; d < 64; d <<= 1) { s += __shfl_xor(s, d); sq += __shfl_xor(sq, d); }
      float mean = s * (1.0f / 256.0f);
      float var = sq * (1.0f / 256.0f) - mean * mean;
      float is = 1.0f / sqrtf(var + 1e-5f);
      const float* g = rls + layer * 256;
      const float* bb = rlb + layer * 256;
      bf4 o;
#pragma unroll
      for (int e = 0; e < 4; ++e)
        o[e] = (short)f2bf((h0[e] - mean) * is * g[c + e] + bb[c + e]);
      *(bf4*)&As[row * AST + c] = o;
    }
    __syncthreads();  // As ready

    // GEMM1: Ys = relu(As @ W1^T + b1); consume wp(=W1[layer]), refill W2[layer]
    {
      f32x4 acc0 = {0.f, 0.f, 0.f, 0.f}, acc1 = acc0;
#pragma unroll
      for (int i = 0; i < 8; ++i) {
        bf8 a = *(const bf8*)&As[ar * AST + i * 32 + wq8];
        acc0 = mfma16(a, wp0[i], acc0);
        acc1 = mfma16(a, wp1[i], acc1);
        wp0[i] = *(const bf8*)(W2a + (size_t)layer * 65536 + i * 32);
        wp1[i] = *(const bf8*)(W2b + (size_t)layer * 65536 + i * 32);
      }
      float bi0 = rb1[layer * 256 + wn + lrow];
      float bi1 = rb1[layer * 256 + wn + 16 + lrow];
#pragma unroll
      for (int r = 0; r < 4; ++r) {
        int rr = quad * 4 + r;
        if (rr < 8) {
          Ys[rr * YST + wn + lrow] = f2bf(fmaxf(acc0[r] + bi0, 0.f));
          Ys[rr * YST + wn + 16 + lrow] = f2bf(fmaxf(acc1[r] + bi1, 0.f));
        }
      }
    }
    __syncthreads();  // Ys ready

    // GEMM2: h = (h + Ys @ W2^T + b2) * rsqrt2; consume wp, refill W1[layer+1]
    {
      f32x4 acc0 = {0.f, 0.f, 0.f, 0.f}, acc1 = acc0;
#pragma unroll
      for (int i = 0; i < 8; ++i) {
        bf8 a = *(const bf8*)&Ys[ar * YST + i * 32 + wq8];
        acc0 = mfma16(a, wp0[i], acc0);
        acc1 = mfma16(a, wp1[i], acc1);
        if (layer < 2) {
          wp0[i] = *(const bf8*)(W1a + (size_t)(layer + 1) * 65536 + i * 32);
          wp1[i] = *(const bf8*)(W1b + (size_t)(layer + 1) * 65536 + i * 32);
        }
      }
      float bi0 = rb2[layer * 256 + wn + lrow];
      float bi1 = rb2[layer * 256 + wn + 16 + lrow];
#pragma unroll
      for (int r = 0; r < 4; ++r) {
        int rr = quad * 4 + r;
        if (rr < 8) {
          float* h0 = &Hs[rr * HST + wn + lrow];
          float* h1 = &Hs[rr * HST + wn + 16 + lrow];
          *h0 = (*h0 + acc0[r] + bi0) * RSQRT2;
          *h1 = (*h1 + acc1[r] + bi1) * RSQRT2;
        }
      }
    }
    __syncthreads();  // Hs updated for all waves
  }

  // ---- head: wave r owns row r; lanes 0-19 compute one logit each ----
  if (lane < 20) {
    const float* hrow = &Hs[row * HST];
    const float* wrow = hw + (size_t)lane * 256;
    float l0 = 0.f, l1 = 0.f, l2 = 0.f, l3 = 0.f;
    for (int k = 0; k < 256; k += 16) {
      f32x4 h0 = *(const f32x4*)&hrow[k];
      f32x4 h1 = *(const f32x4*)&hrow[k + 4];
      f32x4 h2 = *(const f32x4*)&hrow[k + 8];
      f32x4 h3 = *(const f32x4*)&hrow[k + 12];
      f32x4 w0 = *(const f32x4*)&wrow[k];
      f32x4 w1 = *(const f32x4*)&wrow[k + 4];
      f32x4 w2 = *(const f32x4*)&wrow[k + 8];
      f32x4 w3 = *(const f32x4*)&wrow[k + 12];
#pragma unroll
      for (int e = 0; e < 4; ++e) {
        l0 += h0[e] * w0[e];
        l1 += h1[e] * w1[e];
        l2 += h2[e] * w2[e];
        l3 += h3[e] * w3[e];
      }
    }
    out_lg[(size_t)nrow * 20 + lane] = l0 + l1 + l2 + l3 + hb[lane];
  }
}

// ------- outx for rows NOT covered by pm (inv[n] < 0): out_x = LN(x) --------
__global__ __launch_bounds__(256) void outx_k(
    const float* __restrict__ x, const int* __restrict__ inv,
    const float* __restrict__ g, const float* __restrict__ bb,
    float* __restrict__ out) {
  __shared__ float red[256];
  int n = blockIdx.x, tid = threadIdx.x;
  if (inv[n] >= 0) return;  // covered rows written by mlp_fused
  float v = x[(size_t)n * 256 + tid];
  red[tid] = v;
  __syncthreads();
  for (int off = 128; off; off >>= 1) {
    if (tid < off) red[tid] += red[tid + off];
    __syncthreads();
  }
  float mean = red[0] * (1.0f / 256.0f);
  __syncthreads();
  red[tid] = v * v;
  __syncthreads();
  for (int off = 128; off; off >>= 1) {
    if (tid < off) red[tid] += red[tid + off];
    __syncthreads();
  }
  float var = red[0] * (1.0f / 256.0f) - mean * mean;
  float is = 1.0f / sqrtf(var + 1e-5f);
  out[(size_t)n * 256 + tid] = (v - mean) * is * g[tid] + bb[tid];
}

// ---------------- index compaction -------------------------------------------
__global__ void init_idx_k(int* __restrict__ list, int* __restrict__ inv,
                           int* __restrict__ cnt, int N, int B) {
  int i = blockIdx.x * 256 + threadIdx.x;
  if (i < B * N) list[i] = -1;
  if (i < N) inv[i] = -1;
  if (i < B) cnt[i] = 0;
}

__global__ void compact_k(const int* __restrict__ pm,
                          const int* __restrict__ batch, int* __restrict__ list,
                          int* __restrict__ inv, int* __restrict__ cnt, int N) {
  int m = blockIdx.x * 256 + threadIdx.x;
  if (m >= N) return;
  int p = pm[m];
  int b = batch[p];
  int slot = atomicAdd(&cnt[b], 1);
  list[(size_t)b * N + slot] = m;
  inv[p] = m;
}

// -----------------------------------------------------------------------------
extern "C" void kernel_launch(void* const* d_in, const int* in_sizes, int n_in,
                              void* d_out, int out_size, void* d_ws,
                              size_t ws_size, hipStream_t stream) {
  const float* x = (const float*)d_in[0];
  const float* emb = (const float*)d_in[1];
  const float* mask = (const float*)d_in[2];
  const int* pm = (const int*)d_in[3];
  const int* batch = (const int*)d_in[4];
  const float* Wq = (const float*)d_in[5];
  const float* Wk = (const float*)d_in[6];
  const float* Wv = (const float*)d_in[7];
  const float* ag_s = (const float*)d_in[8];
  const float* ag_b = (const float*)d_in[9];
  const float* Wag = (const float*)d_in[10];
  const float* rls = (const float*)d_in[11];
  const float* rlb = (const float*)d_in[12];
  const float* rw1 = (const float*)d_in[13];
  const float* rb1 = (const float*)d_in[14];
  const float* rw2 = (const float*)d_in[15];
  const float* rb2 = (const float*)d_in[16];
  const float* hw = (const float*)d_in[17];
  const float* hb = (const float*)d_in[18];
  const float* ens = (const float*)d_in[19];
  const float* enb = (const float*)d_in[20];

  const int N = in_sizes[0] / 256;  // 4096
  const int B = in_sizes[2] / 512;  // 4

  char* wsb = (char*)d_ws;
  // conversion-phase (dead before packed is written):
  u16* embbf = (u16*)(wsb + 0);
  u16* xbf   = (u16*)(wsb + 5242880);
  u16* Wkvbf = (u16*)(wsb + 7340032);
  u16* Wqbf  = (u16*)(wsb + 9961472);
  // attention phase:
  u16* packed = (u16*)(wsb + 0);           // 32 MB
  u16* KVbf   = (u16*)(wsb + 33554432);    // 4 MB
  u16* Qbf    = (u16*)(wsb + 37748736);    // 4 MB
  u16* VT     = (u16*)(wsb + 41943040);    // 2 MB
  u16* featE  = (u16*)(wsb + 44040192);    // 4 MB
  // persistent:
  u16* Wagbf = (u16*)(wsb + 48234496);
  u16* rw1bf = (u16*)(wsb + 48496640);
  u16* rw2bf = (u16*)(wsb + 48889856);
  int* list  = (int*)(wsb + 49545216);
  int* inv   = (int*)(wsb + 49610752);
  int* cnt   = (int*)(wsb + 49627136);

  float* out_x = (float*)d_out;
  float* out_lg = out_x + (size_t)N * 256;
  float* out_sc = out_lg + (size_t)N * 20;

  // 0. conversions + index compaction
  CvtArgs ca;
  ca.d[0] = {emb, embbf, 2 * 512 * 1280 * 2};
  ca.d[1] = {x, xbf, 4096 * 256};
  ca.d[2] = {Wk, Wkvbf, 512 * 1280};
  ca.d[3] = {Wv, Wkvbf + 512 * 1280, 512 * 1280};
  ca.d[4] = {Wq, Wqbf, 512 * 256};
  ca.d[5] = {Wag, Wagbf, 256 * 512};
  ca.d[6] = {rw1, rw1bf, 3 * 256 * 256};
  ca.d[7] = {rw2, rw2bf, 3 * 256 * 256};
  cvt_k<<<dim3(1281, 1, 8), 256, 0, stream>>>(ca);
  init_idx_k<<<(B * N + 255) / 256, 256, 0, stream>>>(list, inv, cnt, N, B);
  compact_k<<<(N + 255) / 256, 256, 0, stream>>>(pm, batch, list, inv, cnt, N);

  // 1. fused K+V projection (64-row tiles: 512 blocks, 2/CU)
  mgemm2<EPI_NONE, true, 64><<<dim3(16, B * 8), 256, 0, stream>>>(
      embbf, Wkvbf, KVbf, B * 512, 1024, 1280, 1280, 1280, 1024,
      nullptr, nullptr, nullptr, nullptr);
  // 2. Q projection with gather (64-row tiles: 512 blocks, 2/CU)
  mgemm2<EPI_NONE, true, 64><<<dim3(8, N / 64), 256, 0, stream>>>(
      xbf, Wqbf, Qbf, N, 512, 256, 256, 256, 512,
      nullptr, nullptr, pm, nullptr);
  vtrans<<<dim3(16, 16, B), 256, 0, stream>>>(KVbf, VT);

  // 3. fused attention (scores+softmax+PV), then unpack for the fp32 output
  attn_fused<<<dim3(N / 32, B * 8), 256, 0, stream>>>(
      Qbf, KVbf, VT, list, mask, packed, featE, N);
  unpack_k<<<N, 256, 0, stream>>>(packed, pm, out_sc, N);

  // 4+5+6+7. fused LN512 + AG GEMM + out_x + residual MLP + head
  // (8 rows/block, 512 blocks = 2 independent chains per CU)
  mlp_fused<<<dim3(N / 8), 512, 0, stream>>>(
      featE, ag_s, ag_b, Wagbf, x, ens, enb, rls, rlb, rw1bf, rb1,
      rw2bf, rb2, hw, hb, pm, out_lg, out_x);

  // 7b. out_x for rows not covered by pm (early-exit when all covered)
  outx_k<<<N, 256, 0, stream>>>(x, inv, ens, enb, out_x);
}

// Round 13
// 283.421 us; speedup vs baseline: 1.1615x; 1.1615x over previous
//
#include <hip/hip_runtime.h>
#include <math.h>

// Round 18: revert to round-15 best (attn staged 2-barrier + XCD swizzle;
// mlp 16-row/1024-thread with weight prefetch + fused outx) and MERGE
// unpack into mlp's dispatch: grid 256+1024, blocks <256 run the mlp chain
// (latency-bound, CU half-idle), blocks >=256 unpack 4 rows each (pure
// memory) — the scheduler packs them into the idle slots so unpack's
// ~15-20us of traffic hides under mlp's barrier stalls. unpack_k deleted.

typedef short bf8 __attribute__((ext_vector_type(8)));
typedef short bf4 __attribute__((ext_vector_type(4)));
typedef float f32x4 __attribute__((ext_vector_type(4)));
typedef unsigned short u16;

constexpr int LDT = 40;  // LDS row stride in shorts (32 data + 8 pad)
enum { EPI_NONE = 0, EPI_BIAS_RELU = 1, EPI_BIAS = 2, EPI_RESID = 3 };
#define RSQRT2 0.70710678118654752f

__device__ __forceinline__ u16 f2bf(float f) {
  unsigned int u = __builtin_bit_cast(unsigned int, f);
  unsigned int r = u + 0x7fffu + ((u >> 16) & 1u);  // RNE
  return (u16)(r >> 16);
}
__device__ __forceinline__ float bf2f(u16 v) {
  return __builtin_bit_cast(float, (unsigned int)v << 16);
}
__device__ __forceinline__ f32x4 mfma16(bf8 a, bf8 b, f32x4 c) {
  return __builtin_amdgcn_mfma_f32_16x16x32_bf16(a, b, c, 0, 0, 0);
}

// ---------------- batched f32 -> bf16 conversion -----------------------------
struct CvtDesc { const float* src; u16* dst; int n; };
struct CvtArgs { CvtDesc d[8]; };

__global__ __launch_bounds__(256) void cvt_k(CvtArgs a) {
  CvtDesc d = a.d[blockIdx.z];
  int i = (blockIdx.x * 256 + threadIdx.x) * 8;
  if (i >= d.n) return;
  f32x4 v0 = *(const f32x4*)(d.src + i);
  f32x4 v1 = *(const f32x4*)(d.src + i + 4);
  bf8 o;
  o[0] = (short)f2bf(v0[0]); o[1] = (short)f2bf(v0[1]);
  o[2] = (short)f2bf(v0[2]); o[3] = (short)f2bf(v0[3]);
  o[4] = (short)f2bf(v1[0]); o[5] = (short)f2bf(v1[1]);
  o[6] = (short)f2bf(v1[2]); o[7] = (short)f2bf(v1[3]);
  *(bf8*)(d.dst + i) = o;
}

// ------- MTxN-tile bf16 GEMM: C[M,N] = A[M,K](bf16) @ B[N,K](bf16)^T --------
template <int EPI, bool BFOUT, int MT>
__global__ __launch_bounds__(256) void mgemm2(
    const u16* __restrict__ A, const u16* __restrict__ B,
    void* __restrict__ Cv, int M, int N, int K, int lda, int ldb, int ldc,
    const float* __restrict__ bias, const float* __restrict__ Hin,
    const int* __restrict__ gatherA, const int* __restrict__ scatterC) {
  constexpr int NF = MT / 32;  // m-frags per wave
  __shared__ __align__(16) u16 As[MT * LDT];
  __shared__ __align__(16) u16 Bs[64 * LDT];
  const int tid = threadIdx.x;
  const int m0 = blockIdx.y * MT, n0 = blockIdx.x * 64;
  const int wave = tid >> 6, lane = tid & 63;
  const int wm = (wave & 1) * (MT / 2), wn = (wave >> 1) * 32;
  const int lrow = lane & 15, quad = lane >> 4;
  const int srow = tid >> 2, skq = tid & 3;

  int gr0 = m0 + srow;
  int ar0 = (gr0 < M) ? (gatherA ? gatherA[gr0] : gr0) : -1;
  const u16* Ap0 = (ar0 >= 0) ? A + (size_t)ar0 * lda + skq * 8 : nullptr;
  const u16* Ap1 = nullptr;
  if constexpr (MT == 128) {
    int gr1 = m0 + srow + 64;
    int ar1 = (gr1 < M) ? (gatherA ? gatherA[gr1] : gr1) : -1;
    Ap1 = (ar1 >= 0) ? A + (size_t)ar1 * lda + skq * 8 : nullptr;
  }
  const u16* Bp = (n0 + srow < N) ? B + (size_t)(n0 + srow) * ldb + skq * 8 : nullptr;
  u16* AsW0 = &As[srow * LDT + skq * 8];
  u16* AsW1 = (MT == 128) ? &As[(srow + 64) * LDT + skq * 8] : nullptr;
  u16* BsW = &Bs[srow * LDT + skq * 8];

  f32x4 acc[NF][2];
#pragma unroll
  for (int i = 0; i < NF; ++i)
#pragma unroll
    for (int j = 0; j < 2; ++j) acc[i][j] = (f32x4){0.f, 0.f, 0.f, 0.f};
  const bf8 z8 = {0, 0, 0, 0, 0, 0, 0, 0};

  for (int k0 = 0; k0 < K; k0 += 32) {
    bf8 a0 = Ap0 ? *(const bf8*)(Ap0 + k0) : z8;
    bf8 bv = Bp ? *(const bf8*)(Bp + k0) : z8;
    *(bf8*)AsW0 = a0;
    if constexpr (MT == 128) {
      bf8 a1 = Ap1 ? *(const bf8*)(Ap1 + k0) : z8;
      *(bf8*)AsW1 = a1;
    }
    *(bf8*)BsW = bv;
    __syncthreads();
    bf8 af[NF], bfr[2];
#pragma unroll
    for (int i = 0; i < NF; ++i)
      af[i] = *(const bf8*)&As[(wm + i * 16 + lrow) * LDT + quad * 8];
#pragma unroll
    for (int j = 0; j < 2; ++j)
      bfr[j] = *(const bf8*)&Bs[(wn + j * 16 + lrow) * LDT + quad * 8];
#pragma unroll
    for (int i = 0; i < NF; ++i)
#pragma unroll
      for (int j = 0; j < 2; ++j) acc[i][j] = mfma16(af[i], bfr[j], acc[i][j]);
    __syncthreads();
  }

  float* Cf = (float*)Cv;
  u16* Cb = (u16*)Cv;
#pragma unroll
  for (int i = 0; i < NF; ++i) {
#pragma unroll
    for (int r = 0; r < 4; ++r) {
      int row = m0 + wm + i * 16 + quad * 4 + r;
      if (row >= M) continue;
      if (gatherA && gatherA[row] < 0) continue;
      int orow = scatterC ? scatterC[row] : row;
#pragma unroll
      for (int j = 0; j < 2; ++j) {
        int col = n0 + wn + j * 16 + lrow;
        if (col >= N) continue;
        float v = acc[i][j][r];
        if (EPI == EPI_BIAS_RELU) v = fmaxf(v + bias[col], 0.f);
        else if (EPI == EPI_BIAS) v += bias[col];
        else if (EPI == EPI_RESID) v = (Hin[(size_t)row * ldc + col] + v + bias[col]) * RSQRT2;
        if (BFOUT) Cb[(size_t)orow * ldc + col] = f2bf(v);
        else Cf[(size_t)orow * ldc + col] = v;
      }
    }
  }
}

// ---------------- V transpose: KV[b][s][512+hd] -> VT[b][hd][s] (bf16) -------
__global__ __launch_bounds__(256) void vtrans(const u16* __restrict__ KV,
                                              u16* __restrict__ VT) {
  __shared__ u16 t[32][33];
  int b = blockIdx.z;
  int s0 = blockIdx.x * 32, d0 = blockIdx.y * 32;
  int tx = threadIdx.x & 31, ty = threadIdx.x >> 5;
#pragma unroll
  for (int i = 0; i < 32; i += 8)
    t[ty + i][tx] = KV[(size_t)(b * 512 + s0 + ty + i) * 1024 + 512 + d0 + tx];
  __syncthreads();
#pragma unroll
  for (int i = 0; i < 32; i += 8)
    VT[(size_t)(b * 512 + d0 + ty + i) * 512 + s0 + tx] = t[tx][ty + i];
}

// ---------------- fused attention: per (b,h,mtile32) -------------------------
// Round-15 staged structure + XCD swizzle.
constexpr int WST = 520;  // W row stride (512 + 8 pad) -> 65 granules (odd)
constexpr int QST = 72;   // Q/K/V row stride (64 + 8 pad) -> 9 granules (odd)

__global__ __launch_bounds__(256) void attn_fused(
    const u16* __restrict__ Q, const u16* __restrict__ KV,
    const u16* __restrict__ VT, const int* __restrict__ list,
    const float* __restrict__ mask, u16* __restrict__ packed,
    u16* __restrict__ feat, int N) {
  // XCD-aware decode: lin = xcd + 8*(mt + NMT*(y>>3)); y = (group<<3)|xcd
  const int NMT = gridDim.x;              // mt tiles per (b,h)
  const int lin = blockIdx.y * NMT + blockIdx.x;
  const int xcd = lin & 7, rest = lin >> 3;
  const int mt = rest % NMT;
  const int y = ((rest / NMT) << 3) | xcd;
  const int b = y >> 3, h = y & 7;
  const int* lst = list + (size_t)b * N + mt * 32;
  if (lst[0] < 0) return;

  __shared__ __align__(16) u16 Ws[32 * WST];
  __shared__ __align__(16) u16 Qs[32 * QST];
  __shared__ __align__(16) u16 KVs[64 * QST];  // K tiles (A) / V chunks (B)
  __shared__ __align__(16) float mk[8][68];    // mask, padded
  __shared__ int mS[32];

  const int tid = threadIdx.x;
  const int wave = tid >> 6, lane = tid & 63;
  const int wm = (wave & 1) * 16, wns = (wave >> 1) * 32;
  const int lrow = lane & 15, quad = lane >> 4;
  const bf8 z8 = {0, 0, 0, 0, 0, 0, 0, 0};

  // staging lane geometry (shared by Phase A / Phase B)
  const int c0 = tid * 2, c1 = tid * 2 + 1;
  const int sr0 = c0 >> 3, kq0 = c0 & 7;
  const int sr1 = c1 >> 3, kq1 = c1 & 7;
  u16* kvw0 = &KVs[sr0 * QST + kq0 * 8];
  u16* kvw1 = &KVs[sr1 * QST + kq1 * 8];

  if (tid < 32) mS[tid] = lst[tid];
  {  // stage mask into padded layout (float2 per thread)
    int p = tid >> 5, j = (tid & 31) * 2;
    *(float2*)&mk[p][j] = *(const float2*)&mask[(size_t)b * 512 + p * 64 + j];
  }
  {  // stage Q tile: 32 rows x 64k
    int qr = tid >> 3, kq = tid & 7;
    int m = lst[qr];
    *(bf8*)&Qs[qr * QST + kq * 8] =
        (m >= 0) ? *(const bf8*)(Q + (size_t)m * 512 + h * 64 + kq * 8) : z8;
  }
  const u16* KVb = KV + (size_t)(b * 512) * 1024 + h * 64;
  {  // prologue: stage K tile rot(0) directly (overlaps Q/mask staging above)
    int sta = mt & 7;
    *(bf8*)kvw0 = *(const bf8*)(KVb + (size_t)(sta * 64 + sr0) * 1024 + kq0 * 8);
    *(bf8*)kvw1 = *(const bf8*)(KVb + (size_t)(sta * 64 + sr1) * 1024 + kq1 * 8);
  }
  __syncthreads();

  const bf8 qa0 = *(const bf8*)&Qs[(wm + lrow) * QST + 0 + quad * 8];
  const bf8 qa1 = *(const bf8*)&Qs[(wm + lrow) * QST + 32 + quad * 8];

  // ---- Phase A: scores; next tile loaded to regs under the MFMA (T14) ----
  bf8 r0, r1;
  for (int st = 0; st < 8; ++st) {
    const int sta = (st + mt) & 7;
    if (st < 7) {  // issue next-tile loads; drained at the barrier below
      int nx = (st + 1 + mt) & 7;
      r0 = *(const bf8*)(KVb + (size_t)(nx * 64 + sr0) * 1024 + kq0 * 8);
      r1 = *(const bf8*)(KVb + (size_t)(nx * 64 + sr1) * 1024 + kq1 * 8);
    }
    f32x4 acc0 = {0.f, 0.f, 0.f, 0.f}, acc1 = acc0;
    {
      bf8 b00 = *(const bf8*)&KVs[(wns + lrow) * QST + quad * 8];
      bf8 b10 = *(const bf8*)&KVs[(wns + 16 + lrow) * QST + quad * 8];
      bf8 b01 = *(const bf8*)&KVs[(wns + lrow) * QST + 32 + quad * 8];
      bf8 b11 = *(const bf8*)&KVs[(wns + 16 + lrow) * QST + 32 + quad * 8];
      __builtin_amdgcn_s_setprio(1);
      acc0 = mfma16(qa0, b00, acc0);
      acc1 = mfma16(qa0, b10, acc1);
      acc0 = mfma16(qa1, b01, acc0);
      acc1 = mfma16(qa1, b11, acc1);
      __builtin_amdgcn_s_setprio(0);
    }
#pragma unroll
    for (int r = 0; r < 4; ++r) {
      int lr = wm + quad * 4 + r;
      Ws[lr * WST + sta * 64 + wns + lrow] = f2bf(acc0[r] * 0.125f);
      Ws[lr * WST + sta * 64 + wns + 16 + lrow] = f2bf(acc1[r] * 0.125f);
    }
    __syncthreads();  // KVs reads done + Ws visible (+ r0/r1 arrived)
    if (st < 7) {
      *(bf8*)kvw0 = r0;
      *(bf8*)kvw1 = r1;
      __syncthreads();  // next tile ready
    }
  }

  // Phase-B prologue: first V chunk loads issued BEFORE stats (hidden there)
  const u16* VTb = VT + (size_t)(b * 512 + h * 64) * 512;
  bf8 v0p = *(const bf8*)(VTb + (size_t)sr0 * 512 + ((mt & 7) << 6) + kq0 * 8);
  bf8 v1p = *(const bf8*)(VTb + (size_t)sr1 * 512 + ((mt & 7) << 6) + kq1 * 8);

  // ---- Stats + W rebuild: exp values cached in VGPRs across passes ----
  {
    const int row = tid >> 3, part = tid & 7;
    u16* wrow = &Ws[row * WST + part * 64];
    const int mm = mS[row];
    bf8 w[8];
    float mx = -1e30f;
#pragma unroll
    for (int v = 0; v < 8; ++v) {
      w[v] = *(const bf8*)(wrow + v * 8);
#pragma unroll
      for (int j = 0; j < 8; ++j) mx = fmaxf(mx, bf2f((u16)w[v][j]));
    }
    if (mm >= 0) {  // packed raw scores, 16B coalesced stores
      u16* prow = packed + ((size_t)h * N + mm) * 512 + part * 64;
#pragma unroll
      for (int v = 0; v < 8; ++v) *(bf8*)(prow + v * 8) = w[v];
    }
#pragma unroll
    for (int d = 1; d < 8; d <<= 1) mx = fmaxf(mx, __shfl_xor(mx, d));
    float ev[64];
    float se = 0.f, ms = 0.f;
#pragma unroll
    for (int v = 0; v < 8; ++v) {
      f32x4 m0 = *(const f32x4*)&mk[part][v * 8];
      f32x4 m1 = *(const f32x4*)&mk[part][v * 8 + 4];
#pragma unroll
      for (int j = 0; j < 8; ++j) {
        float e = __expf(bf2f((u16)w[v][j]) - mx);
        ev[v * 8 + j] = e;
        se += e;
        ms += e * (j < 4 ? m0[j] : m1[j - 4]);
      }
    }
#pragma unroll
    for (int d = 1; d < 8; d <<= 1) {
      se += __shfl_xor(se, d);
      ms += __shfl_xor(ms, d);
    }
    float iv = 1.0f / (ms + 1e-6f * se);
#pragma unroll
    for (int v = 0; v < 8; ++v) {
      f32x4 m0 = *(const f32x4*)&mk[part][v * 8];
      f32x4 m1 = *(const f32x4*)&mk[part][v * 8 + 4];
      bf8 o;
#pragma unroll
      for (int j = 0; j < 8; ++j)
        o[j] = (short)f2bf(ev[v * 8 + j] * (j < 4 ? m0[j] : m1[j - 4]) * iv);
      *(bf8*)(wrow + v * 8) = o;
    }
  }
  __syncthreads();  // Ws rebuilt visible; Phase-A KVs reads long done
  *(bf8*)kvw0 = v0p;
  *(bf8*)kvw1 = v1p;
  __syncthreads();  // V chunk rot(0) ready

  // ---- Phase B: feat = W @ VT^T (32m x 64d, K=512), reg-prefetched ----
  f32x4 acc0 = {0.f, 0.f, 0.f, 0.f}, acc1 = acc0;
  for (int ss = 0; ss < 8; ++ss) {
    const int s0 = ((ss + mt) & 7) << 6;
    if (ss < 7) {  // issue next-chunk loads; drained at the barrier below
      int nx = ((ss + 1 + mt) & 7) << 6;
      v0p = *(const bf8*)(VTb + (size_t)sr0 * 512 + nx + kq0 * 8);
      v1p = *(const bf8*)(VTb + (size_t)sr1 * 512 + nx + kq1 * 8);
    }
#pragma unroll
    for (int k0 = 0; k0 < 64; k0 += 32) {
      bf8 a = *(const bf8*)&Ws[(wm + lrow) * WST + s0 + k0 + quad * 8];
      bf8 b0 = *(const bf8*)&KVs[(wns + lrow) * QST + k0 + quad * 8];
      bf8 b1 = *(const bf8*)&KVs[(wns + 16 + lrow) * QST + k0 + quad * 8];
      __builtin_amdgcn_s_setprio(1);
      acc0 = mfma16(a, b0, acc0);
      acc1 = mfma16(a, b1, acc1);
      __builtin_amdgcn_s_setprio(0);
    }
    __syncthreads();  // KVs reads done (+ v0p/v1p arrived)
    if (ss < 7) {
      *(bf8*)kvw0 = v0p;
      *(bf8*)kvw1 = v1p;
      __syncthreads();  // next chunk ready
    }
  }
#pragma unroll
  for (int r = 0; r < 4; ++r) {
    int lr = wm + quad * 4 + r;
    int mm = mS[lr];
    if (mm < 0) continue;
    u16* frow = feat + (size_t)mm * 512 + h * 64;
    frow[wns + lrow] = f2bf(acc0[r]);
    frow[wns + 16 + lrow] = f2bf(acc1[r]);
  }
}

// ------- merged: mlp chain (blocks < nmlp) + unpack (blocks >= nmlp) ---------
// mlp body: LN512(feat) -> ag -> out_x -> 3x residual MLP -> head; 16 rows,
// 16 waves, weight prefetch (round-16 version). unpack body: 4 m-rows per
// block via 4x256-thread groups (exact unpack_k logic). One dispatch so the
// scheduler packs memory-bound unpack blocks into the CU slots the
// latency-bound mlp chain leaves idle.
constexpr int HST = 268;   // Hs row stride in floats (67 granules, odd)
constexpr int AST = 520;   // As row stride in shorts (65 granules, odd)
constexpr int YST = 280;   // Ys row stride in shorts (35 granules, odd)
// shared arena: mlp = 16*268*4 + 16*520*2 + 16*280*2 = 42752 B
//               unpack = 4*8*520*2 = 33280 B  -> max 42752
constexpr int SMEM_BYTES = 16 * HST * 4 + 16 * AST * 2 + 16 * YST * 2;

__global__ __launch_bounds__(1024) void mlp_unpack(
    const u16* __restrict__ feat, const float* __restrict__ ag_s,
    const float* __restrict__ ag_b, const u16* __restrict__ Wag,
    const float* __restrict__ x, const float* __restrict__ ens,
    const float* __restrict__ enb, const float* __restrict__ rls,
    const float* __restrict__ rlb, const u16* __restrict__ rw1,
    const float* __restrict__ rb1, const u16* __restrict__ rw2,
    const float* __restrict__ rb2, const float* __restrict__ hw,
    const float* __restrict__ hb, const int* __restrict__ pm,
    const u16* __restrict__ packed, float* __restrict__ out_sc,
    float* __restrict__ out_lg, float* __restrict__ out_x,
    int nmlp, int N) {
  __shared__ __align__(16) char smem[SMEM_BYTES];
  const int tid = threadIdx.x;

  if (blockIdx.x >= nmlp) {
    // ---------------- unpack body: 4 m-rows, 256 threads each ----------------
    u16* Ls = (u16*)smem;  // [4][8*520]
    const int g = tid >> 8, t = tid & 255;
    const int m = (blockIdx.x - nmlp) * 4 + g;
    u16* Lg = Ls + g * (8 * 520);
    int h = t >> 5, c = (t & 31) * 16;
    const u16* row = packed + ((size_t)h * N + m) * 512 + c;
    *(bf8*)&Lg[h * 520 + c] = *(const bf8*)row;
    *(bf8*)&Lg[h * 520 + c + 8] = *(const bf8*)(row + 8);
    __syncthreads();
    float* orow = out_sc + (size_t)pm[m] * 4096;
#pragma unroll
    for (int i = 0; i < 16; ++i) {
      int e = t + i * 256;
      orow[e] = bf2f(Lg[(e & 7) * 520 + (e >> 3)]);
    }
    return;
  }

  // ------------------------------ mlp body -----------------------------------
  float* Hs = (float*)smem;                            // 16*HST floats
  u16* As = (u16*)(smem + 16 * HST * 4);               // 16*AST shorts
  u16* Ys = (u16*)(smem + 16 * HST * 4 + 16 * AST * 2);  // 16*YST shorts
  const int m0 = blockIdx.x * 16;
  const int wave = tid >> 6, lane = tid & 63;
  const int lrow = lane & 15, quad = lane >> 4;
  const int wn = wave * 16;   // this wave's 16 output cols
  const int row = wave;       // LN/outx/head: wave r owns row r
  const int wq8 = quad * 8;
  const int nrow = pm[m0 + row];  // original row index for this wave's row

  // per-thread weight-fragment row pointers (W row = wn+lrow, k chunk = quad)
  const u16* WagW = Wag + (size_t)(wn + lrow) * 512 + wq8;
  const u16* W1W = rw1 + (size_t)(wn + lrow) * 256 + wq8;   // + layer*65536
  const u16* W2W = rw2 + (size_t)(wn + lrow) * 256 + wq8;

  // prefetch AG first half (k = 0..255) — hidden under LN512 + barrier
  bf8 wp[8];
#pragma unroll
  for (int i = 0; i < 8; ++i) wp[i] = *(const bf8*)(WagW + i * 32);

  // ---- LN512(feat) -> As (bf16), 8 cols per lane ----
  {
    const u16* frow = feat + (size_t)(m0 + row) * 512 + lane * 8;
    bf8 f0 = *(const bf8*)frow;
    float s = 0.f, sq = 0.f;
#pragma unroll
    for (int j = 0; j < 8; ++j) {
      float a = bf2f((u16)f0[j]);
      s += a;
      sq += a * a;
    }
#pragma unroll
    for (int d = 1; d < 64; d <<= 1) { s += __shfl_xor(s, d); sq += __shfl_xor(sq, d); }
    float mean = s * (1.0f / 512.0f);
    float var = sq * (1.0f / 512.0f) - mean * mean;
    float is = 1.0f / sqrtf(var + 1e-5f);
    int c = lane * 8;
    bf8 o0;
#pragma unroll
    for (int j = 0; j < 8; ++j)
      o0[j] = (short)f2bf((bf2f((u16)f0[j]) - mean) * is * ag_s[c + j] + ag_b[c + j]);
    *(bf8*)&As[row * AST + c] = o0;
  }
  __syncthreads();

  // ---- AG GEMM: h = ag = LN(feat) @ Wag^T (K=512, two halves of 8) ----
  {
    f32x4 acc = {0.f, 0.f, 0.f, 0.f};
#pragma unroll
    for (int i = 0; i < 8; ++i) {       // consume k 0..255, refill k 256..511
      bf8 a = *(const bf8*)&As[lrow * AST + i * 32 + wq8];
      acc = mfma16(a, wp[i], acc);
      wp[i] = *(const bf8*)(WagW + 256 + i * 32);
    }
#pragma unroll
    for (int i = 0; i < 8; ++i) {       // consume k 256..511, refill W1[0]
      bf8 a = *(const bf8*)&As[lrow * AST + 256 + i * 32 + wq8];
      acc = mfma16(a, wp[i], acc);
      wp[i] = *(const bf8*)(W1W + i * 32);
    }
#pragma unroll
    for (int r = 0; r < 4; ++r) {
      int rr = quad * 4 + r;
      Hs[rr * HST + wn + lrow] = acc[r];
    }
  }
  __syncthreads();  // Hs = ag complete

  // ---- out_x = LN(x + ag/sqrt2) for this block's 16 rows (fused outx) ----
  {
    int c = lane * 4;
    f32x4 xv = *(const f32x4*)&x[(size_t)nrow * 256 + c];
    f32x4 hv = *(const f32x4*)&Hs[row * HST + c];
    f32x4 v;
#pragma unroll
    for (int e = 0; e < 4; ++e) v[e] = xv[e] + hv[e] * RSQRT2;
    float s = v[0] + v[1] + v[2] + v[3];
    float sq = v[0] * v[0] + v[1] * v[1] + v[2] * v[2] + v[3] * v[3];
#pragma unroll
    for (int d = 1; d < 64; d <<= 1) { s += __shfl_xor(s, d); sq += __shfl_xor(sq, d); }
    float mean = s * (1.0f / 256.0f);
    float var = sq * (1.0f / 256.0f) - mean * mean;
    float is = 1.0f / sqrtf(var + 1e-5f);
    f32x4 o;
#pragma unroll
    for (int e = 0; e < 4; ++e)
      o[e] = (v[e] - mean) * is * ens[c + e] + enb[c + e];
    *(f32x4*)&out_x[(size_t)nrow * 256 + c] = o;
  }

  // ---- 3 residual layers ----
  for (int layer = 0; layer < 3; ++layer) {
    // LN(h) -> As (4 cols per lane)   [Hs stable since the barrier above]
    {
      int c = lane * 4;
      f32x4 h0 = *(const f32x4*)&Hs[row * HST + c];
      float s = h0[0] + h0[1] + h0[2] + h0[3];
      float sq = h0[0] * h0[0] + h0[1] * h0[1] + h0[2] * h0[2] + h0[3] * h0[3];
#pragma unroll
      for (int d = 1; d < 64; d <<= 1) { s += __shfl_xor(s, d); sq += __shfl_xor(sq, d); }
      float mean = s * (1.0f / 256.0f);
      float var = sq * (1.0f / 256.0f) - mean * mean;
      float is = 1.0f / sqrtf(var + 1e-5f);
      const float* g = rls + layer * 256;
      const float* bb = rlb + layer * 256;
      bf4 o;
#pragma unroll
      for (int e = 0; e < 4; ++e)
        o[e] = (short)f2bf((h0[e] - mean) * is * g[c + e] + bb[c + e]);
      *(bf4*)&As[row * AST + c] = o;
    }
    __syncthreads();  // As ready

    // GEMM1: Ys = relu(As @ W1^T + b1); consume wp(=W1[layer]), refill W2[layer]
    {
      f32x4 acc = {0.f, 0.f, 0.f, 0.f};
#pragma unroll
      for (int i = 0; i < 8; ++i) {
        bf8 a = *(const bf8*)&As[lrow * AST + i * 32 + wq8];
        acc = mfma16(a, wp[i], acc);
        wp[i] = *(const bf8*)(W2W + (size_t)layer * 65536 + i * 32);
      }
      float bi = rb1[layer * 256 + wn + lrow];
#pragma unroll
      for (int r = 0; r < 4; ++r) {
        int rr = quad * 4 + r;
        Ys[rr * YST + wn + lrow] = f2bf(fmaxf(acc[r] + bi, 0.f));
      }
    }
    __syncthreads();  // Ys ready

    // GEMM2: h = (h + Ys @ W2^T + b2) * rsqrt2; consume wp, refill W1[layer+1]
    {
      f32x4 acc = {0.f, 0.f, 0.f, 0.f};
#pragma unroll
      for (int i = 0; i < 8; ++i) {
        bf8 a = *(const bf8*)&Ys[lrow * YST + i * 32 + wq8];
        acc = mfma16(a, wp[i], acc);
        if (layer < 2)
          wp[i] = *(const bf8*)(W1W + (size_t)(layer + 1) * 65536 + i * 32);
      }
      float bi = rb2[layer * 256 + wn + lrow];
#pragma unroll
      for (int r = 0; r < 4; ++r) {
        int rr = quad * 4 + r;
        float* h0 = &Hs[rr * HST + wn + lrow];
        *h0 = (*h0 + acc[r] + bi) * RSQRT2;
      }
    }
    __syncthreads();  // Hs updated for all waves
  }

  // ---- head: wave r owns row r; lanes 0-19 compute one logit each ----
  if (lane < 20) {
    const float* hrow = &Hs[row * HST];
    const float* wrow = hw + (size_t)lane * 256;
    float l0 = 0.f, l1 = 0.f, l2 = 0.f, l3 = 0.f;
    for (int k = 0; k < 256; k += 16) {
      f32x4 h0 = *(const f32x4*)&hrow[k];
      f32x4 h1 = *(const f32x4*)&hrow[k + 4];
      f32x4 h2 = *(const f32x4*)&hrow[k + 8];
      f32x4 h3 = *(const f32x4*)&hrow[k + 12];
      f32x4 w0 = *(const f32x4*)&wrow[k];
      f32x4 w1 = *(const f32x4*)&wrow[k + 4];
      f32x4 w2 = *(const f32x4*)&wrow[k + 8];
      f32x4 w3 = *(const f32x4*)&wrow[k + 12];
#pragma unroll
      for (int e = 0; e < 4; ++e) {
        l0 += h0[e] * w0[e];
        l1 += h1[e] * w1[e];
        l2 += h2[e] * w2[e];
        l3 += h3[e] * w3[e];
      }
    }
    out_lg[(size_t)nrow * 20 + lane] = l0 + l1 + l2 + l3 + hb[lane];
  }
}

// ------- outx for rows NOT covered by pm (inv[n] < 0): out_x = LN(x) --------
__global__ __launch_bounds__(256) void outx_k(
    const float* __restrict__ x, const int* __restrict__ inv,
    const float* __restrict__ g, const float* __restrict__ bb,
    float* __restrict__ out) {
  __shared__ float red[256];
  int n = blockIdx.x, tid = threadIdx.x;
  if (inv[n] >= 0) return;  // covered rows written by mlp_unpack
  float v = x[(size_t)n * 256 + tid];
  red[tid] = v;
  __syncthreads();
  for (int off = 128; off; off >>= 1) {
    if (tid < off) red[tid] += red[tid + off];
    __syncthreads();
  }
  float mean = red[0] * (1.0f / 256.0f);
  __syncthreads();
  red[tid] = v * v;
  __syncthreads();
  for (int off = 128; off; off >>= 1) {
    if (tid < off) red[tid] += red[tid + off];
    __syncthreads();
  }
  float var = red[0] * (1.0f / 256.0f) - mean * mean;
  float is = 1.0f / sqrtf(var + 1e-5f);
  out[(size_t)n * 256 + tid] = (v - mean) * is * g[tid] + bb[tid];
}

// ---------------- index compaction -------------------------------------------
__global__ void init_idx_k(int* __restrict__ list, int* __restrict__ inv,
                           int* __restrict__ cnt, int N, int B) {
  int i = blockIdx.x * 256 + threadIdx.x;
  if (i < B * N) list[i] = -1;
  if (i < N) inv[i] = -1;
  if (i < B) cnt[i] = 0;
}

__global__ void compact_k(const int* __restrict__ pm,
                          const int* __restrict__ batch, int* __restrict__ list,
                          int* __restrict__ inv, int* __restrict__ cnt, int N) {
  int m = blockIdx.x * 256 + threadIdx.x;
  if (m >= N) return;
  int p = pm[m];
  int b = batch[p];
  int slot = atomicAdd(&cnt[b], 1);
  list[(size_t)b * N + slot] = m;
  inv[p] = m;
}

// -----------------------------------------------------------------------------
extern "C" void kernel_launch(void* const* d_in, const int* in_sizes, int n_in,
                              void* d_out, int out_size, void* d_ws,
                              size_t ws_size, hipStream_t stream) {
  const float* x = (const float*)d_in[0];
  const float* emb = (const float*)d_in[1];
  const float* mask = (const float*)d_in[2];
  const int* pm = (const int*)d_in[3];
  const int* batch = (const int*)d_in[4];
  const float* Wq = (const float*)d_in[5];
  const float* Wk = (const float*)d_in[6];
  const float* Wv = (const float*)d_in[7];
  const float* ag_s = (const float*)d_in[8];
  const float* ag_b = (const float*)d_in[9];
  const float* Wag = (const float*)d_in[10];
  const float* rls = (const float*)d_in[11];
  const float* rlb = (const float*)d_in[12];
  const float* rw1 = (const float*)d_in[13];
  const float* rb1 = (const float*)d_in[14];
  const float* rw2 = (const float*)d_in[15];
  const float* rb2 = (const float*)d_in[16];
  const float* hw = (const float*)d_in[17];
  const float* hb = (const float*)d_in[18];
  const float* ens = (const float*)d_in[19];
  const float* enb = (const float*)d_in[20];

  const int N = in_sizes[0] / 256;  // 4096
  const int B = in_sizes[2] / 512;  // 4

  char* wsb = (char*)d_ws;
  // conversion-phase (dead before packed is written):
  u16* embbf = (u16*)(wsb + 0);
  u16* xbf   = (u16*)(wsb + 5242880);
  u16* Wkvbf = (u16*)(wsb + 7340032);
  u16* Wqbf  = (u16*)(wsb + 9961472);
  // attention phase:
  u16* packed = (u16*)(wsb + 0);           // 32 MB
  u16* KVbf   = (u16*)(wsb + 33554432);    // 4 MB
  u16* Qbf    = (u16*)(wsb + 37748736);    // 4 MB
  u16* VT     = (u16*)(wsb + 41943040);    // 2 MB
  u16* featE  = (u16*)(wsb + 44040192);    // 4 MB
  // persistent:
  u16* Wagbf = (u16*)(wsb + 48234496);
  u16* rw1bf = (u16*)(wsb + 48496640);
  u16* rw2bf = (u16*)(wsb + 48889856);
  int* list  = (int*)(wsb + 49545216);
  int* inv   = (int*)(wsb + 49610752);
  int* cnt   = (int*)(wsb + 49627136);

  float* out_x = (float*)d_out;
  float* out_lg = out_x + (size_t)N * 256;
  float* out_sc = out_lg + (size_t)N * 20;

  // 0. conversions + index compaction
  CvtArgs ca;
  ca.d[0] = {emb, embbf, 2 * 512 * 1280 * 2};
  ca.d[1] = {x, xbf, 4096 * 256};
  ca.d[2] = {Wk, Wkvbf, 512 * 1280};
  ca.d[3] = {Wv, Wkvbf + 512 * 1280, 512 * 1280};
  ca.d[4] = {Wq, Wqbf, 512 * 256};
  ca.d[5] = {Wag, Wagbf, 256 * 512};
  ca.d[6] = {rw1, rw1bf, 3 * 256 * 256};
  ca.d[7] = {rw2, rw2bf, 3 * 256 * 256};
  cvt_k<<<dim3(1281, 1, 8), 256, 0, stream>>>(ca);
  init_idx_k<<<(B * N + 255) / 256, 256, 0, stream>>>(list, inv, cnt, N, B);
  compact_k<<<(N + 255) / 256, 256, 0, stream>>>(pm, batch, list, inv, cnt, N);

  // 1. fused K+V projection (64-row tiles: 512 blocks, 2/CU)
  mgemm2<EPI_NONE, true, 64><<<dim3(16, B * 8), 256, 0, stream>>>(
      embbf, Wkvbf, KVbf, B * 512, 1024, 1280, 1280, 1280, 1024,
      nullptr, nullptr, nullptr, nullptr);
  // 2. Q projection with gather (64-row tiles: 512 blocks, 2/CU)
  mgemm2<EPI_NONE, true, 64><<<dim3(8, N / 64), 256, 0, stream>>>(
      xbf, Wqbf, Qbf, N, 512, 256, 256, 256, 512,
      nullptr, nullptr, pm, nullptr);
  vtrans<<<dim3(16, 16, B), 256, 0, stream>>>(KVbf, VT);

  // 3. fused attention (scores+softmax+PV)
  attn_fused<<<dim3(N / 32, B * 8), 256, 0, stream>>>(
      Qbf, KVbf, VT, list, mask, packed, featE, N);

  // 4-7 + unpack in ONE dispatch: blocks [0,256) run the mlp chain,
  // blocks [256, 256+1024) unpack 4 rows each (fills idle CU slots).
  const int nmlp = N / 16;                 // 256
  const int nunp = N / 4;                  // 1024
  mlp_unpack<<<dim3(nmlp + nunp), 1024, 0, stream>>>(
      featE, ag_s, ag_b, Wagbf, x, ens, enb, rls, rlb, rw1bf, rb1,
      rw2bf, rb2, hw, hb, pm, packed, out_sc, out_lg, out_x, nmlp, N);

  // 7b. out_x for rows not covered by pm (early-exit when all covered)
  outx_k<<<N, 256, 0, stream>>>(x, inv, ens, enb, out_x);
}